// Round 8
// baseline (205.334 us; speedup 1.0000x reference)
//
#include <hip/hip_runtime.h>
#include <cstdint>
#include <cstddef>

// DenseGAT, N=4096, IN_DIM=256, H=4, D=64, NEG_SLOPE=0.2
// w[i,j,h] = eb * max(t5, tt);  tt = ui*uj = exp(.2(ei+ej)),
//   t5 = ui5*uj5 = exp(ei+ej) = tt^5 (exact), eb = exp(bias) or 0 (masked).
// R8: gat_attn gets an explicit register software-pipeline (double-buffered
// 64-j steps) to raise memory-level parallelism ~8x; R7 was depth-1
// latency-bound (0.57 TB/s, VGPR=44). Other kernels unchanged from R7.

typedef _Float16 f16x4 __attribute__((ext_vector_type(4)));
typedef _Float16 f16x8 __attribute__((ext_vector_type(8)));
typedef float f32x4 __attribute__((ext_vector_type(4)));

#define NN 4096
#define CH 4

// ---- Kernel 0: transpose + hi/lo split W -> Wt_hi/Wt_lo (f16) ------------
__global__ __launch_bounds__(256) void wtprep(const float* __restrict__ W,
                                              _Float16* __restrict__ Wth,
                                              _Float16* __restrict__ Wtl) {
  __shared__ float s[64][65];
  const int t = threadIdx.x;
  const int kt = blockIdx.x >> 2, ct = blockIdx.x & 3;
  {
    const int r = t >> 2, cq = (t & 3) * 16;
    #pragma unroll
    for (int q = 0; q < 4; q++) {
      float4 v = *(const float4*)&W[(size_t)(kt * 64 + r) * 256 + ct * 64 + cq + q * 4];
      s[r][cq + q * 4 + 0] = v.x; s[r][cq + q * 4 + 1] = v.y;
      s[r][cq + q * 4 + 2] = v.z; s[r][cq + q * 4 + 3] = v.w;
    }
  }
  __syncthreads();
  {
    const int c = t >> 2, kq = (t & 3) * 16;
    f16x8 hi[2], lo[2];
    #pragma unroll
    for (int g = 0; g < 2; g++)
      #pragma unroll
      for (int kk = 0; kk < 8; kk++) {
        float wv = s[kq + g * 8 + kk][c];
        _Float16 hh = (_Float16)wv;
        hi[g][kk] = hh;
        lo[g][kk] = (_Float16)((wv - (float)hh) * 2048.0f);
      }
    const size_t base = (size_t)(ct * 64 + c) * 256 + kt * 64 + kq;
    *(f16x8*)&Wth[base] = hi[0]; *(f16x8*)&Wth[base + 8] = hi[1];
    *(f16x8*)&Wtl[base] = lo[0]; *(f16x8*)&Wtl[base + 8] = lo[1];
  }
}

// ---- Kernel 1: Wh = h @ W via MFMA hi/lo split; + Vt, ui/uj exps ---------
__global__ __launch_bounds__(256) void gemm_wh(
    const float* __restrict__ A, const _Float16* __restrict__ Wth,
    const _Float16* __restrict__ Wtl, const float* __restrict__ av,
    float* __restrict__ Wh, _Float16* __restrict__ Vt,
    _Float16* __restrict__ uit, _Float16* __restrict__ ui5t,
    _Float16* __restrict__ ujt, _Float16* __restrict__ uj5t) {
  const int tid = threadIdx.x;
  const int lane = tid & 63;
  const int w = __builtin_amdgcn_readfirstlane(tid >> 6);
  const int m = lane & 15, quad = lane >> 4;
  const int mt = blockIdx.x;
  const int head = blockIdx.y;
  const int arow = mt * 64 + w * 16 + m;

  f32x4 dhi[4], dlo[4];
  #pragma unroll
  for (int nt = 0; nt < 4; nt++)
    #pragma unroll
    for (int r = 0; r < 4; r++) { dhi[nt][r] = 0.f; dlo[nt][r] = 0.f; }

  #pragma unroll
  for (int ks = 0; ks < 8; ks++) {
    const float* ap = A + (size_t)arow * 256 + ks * 32 + quad * 8;
    float4 v0 = *(const float4*)ap;
    float4 v1 = *(const float4*)(ap + 4);
    const float vv[8] = {v0.x, v0.y, v0.z, v0.w, v1.x, v1.y, v1.z, v1.w};
    f16x8 ah, al;
    #pragma unroll
    for (int j = 0; j < 8; j++) {
      _Float16 hh = (_Float16)vv[j];
      ah[j] = hh;
      al[j] = (_Float16)((vv[j] - (float)hh) * 2048.0f);
    }
    #pragma unroll
    for (int nt = 0; nt < 4; nt++) {
      const size_t base = (size_t)(head * 64 + nt * 16 + m) * 256 + ks * 32 + quad * 8;
      f16x8 bh = *(const f16x8*)&Wth[base];
      f16x8 bl = *(const f16x8*)&Wtl[base];
      dhi[nt] = __builtin_amdgcn_mfma_f32_16x16x32_f16(ah, bh, dhi[nt], 0, 0, 0);
      dlo[nt] = __builtin_amdgcn_mfma_f32_16x16x32_f16(al, bh, dlo[nt], 0, 0, 0);
      dlo[nt] = __builtin_amdgcn_mfma_f32_16x16x32_f16(ah, bl, dlo[nt], 0, 0, 0);
    }
  }

  f32x4 C[4];
  #pragma unroll
  for (int nt = 0; nt < 4; nt++)
    #pragma unroll
    for (int r = 0; r < 4; r++) C[nt][r] = dhi[nt][r] + dlo[nt][r] * (1.0f / 2048.0f);

  const int crow0 = mt * 64 + w * 16 + quad * 4;
  #pragma unroll
  for (int nt = 0; nt < 4; nt++) {
    #pragma unroll
    for (int r = 0; r < 4; r++)
      Wh[(size_t)(crow0 + r) * 256 + head * 64 + nt * 16 + m] = C[nt][r];
    f16x4 tv;
    #pragma unroll
    for (int r = 0; r < 4; r++) tv[r] = (_Float16)C[nt][r];
    *(f16x4*)&Vt[(size_t)(head * 64 + nt * 16 + m) * NN + crow0] = tv;
  }

  float ai[4], aj[4];
  #pragma unroll
  for (int nt = 0; nt < 4; nt++) {
    ai[nt] = av[head * 128 + nt * 16 + m];
    aj[nt] = av[head * 128 + 64 + nt * 16 + m];
  }
  float pi[4], pj[4];
  #pragma unroll
  for (int r = 0; r < 4; r++) {
    float si = 0.f, sj = 0.f;
    #pragma unroll
    for (int nt = 0; nt < 4; nt++) {
      si = fmaf(C[nt][r], ai[nt], si);
      sj = fmaf(C[nt][r], aj[nt], sj);
    }
    #pragma unroll
    for (int msk = 1; msk <= 8; msk <<= 1) {
      si += __shfl_xor(si, msk, 64);
      sj += __shfl_xor(sj, msk, 64);
    }
    pi[r] = si; pj[r] = sj;
  }
  if (m == 0) {
    #pragma unroll
    for (int r = 0; r < 4; r++) {
      const int row = crow0 + r;
      uit [(size_t)head * NN + row] = (_Float16)__expf(0.2f * pi[r]);
      ui5t[(size_t)head * NN + row] = (_Float16)__expf(pi[r]);
      ujt [(size_t)head * NN + row] = (_Float16)__expf(0.2f * pj[r]);
      uj5t[(size_t)head * NN + row] = (_Float16)__expf(pj[r]);
    }
  }
}

// ---- Kernel 2: fused attention, register-pipelined -----------------------
// grid (256 i-tiles of 16, CH j-chunks), block 256 = 4 waves (wave = head).
// Double-buffered 64-j steps; next step's bias (4x dwordx4) + uj frags are
// in flight while current step computes -> ~4-6 KB in flight per wave.
__global__ __launch_bounds__(256, 4) void gat_attn(
    const float* __restrict__ bias, const _Float16* __restrict__ Vt,
    const _Float16* __restrict__ uit, const _Float16* __restrict__ ui5t,
    const _Float16* __restrict__ ujt, const _Float16* __restrict__ uj5t,
    float* __restrict__ P, float* __restrict__ L) {
  const int itile = blockIdx.x;
  const int chunk = blockIdx.y;
  const int tid = threadIdx.x;
  const int lane = tid & 63;
  const int head = __builtin_amdgcn_readfirstlane(tid >> 6);
  const int m = lane & 15, quad = lane >> 4;
  const int i0 = itile * 16;
  const int j0 = chunk * (NN / CH);

  f32x4 acc[5];
  #pragma unroll
  for (int dt = 0; dt < 5; dt++)
    #pragma unroll
    for (int r = 0; r < 4; r++) acc[dt][r] = 0.f;

  const _Float16 u1 = uit [(size_t)head * NN + i0 + m];
  const _Float16 u5 = ui5t[(size_t)head * NN + i0 + m];
  const f16x8 ui8 = {u1, u1, u1, u1, u1, u1, u1, u1};
  const f16x8 u58 = {u5, u5, u5, u5, u5, u5, u5, u5};
  const f16x8 kOne = {(_Float16)1.f, (_Float16)1.f, (_Float16)1.f, (_Float16)1.f,
                      (_Float16)1.f, (_Float16)1.f, (_Float16)1.f, (_Float16)1.f};

  const float*    bp0 = bias + (size_t)(i0 + m) * NN + j0 + quad * 8;
  const _Float16* ujb = ujt  + (size_t)head * NN + j0 + quad * 8;
  const _Float16* u5b = uj5t + (size_t)head * NN + j0 + quad * 8;
  const _Float16* vb  = Vt   + (size_t)(head * 64 + m) * NN + j0 + quad * 8;

  // pipeline buffers: [buf][half]  (step = 64 j, half = 32 j)
  float4 bbuf[2][4];
  f16x8  ujf[2][2], u5f[2][2];

  // prologue: load step 0 into buf 0
  #pragma unroll
  for (int hh = 0; hh < 2; hh++) {
    bbuf[0][hh * 2 + 0] = *(const float4*)(bp0 + hh * 32);
    bbuf[0][hh * 2 + 1] = *(const float4*)(bp0 + hh * 32 + 4);
    ujf[0][hh] = *(const f16x8*)(ujb + hh * 32);
    u5f[0][hh] = *(const f16x8*)(u5b + hh * 32);
  }

  const int NSTEP = (NN / CH) / 64;   // 16

  #pragma unroll 2
  for (int st = 0; st < NSTEP; st++) {
    const int cur = st & 1, nxt = cur ^ 1;
    // issue next step's loads (stay in flight during compute)
    if (st + 1 < NSTEP) {
      const int jn = (st + 1) * 64;
      #pragma unroll
      for (int hh = 0; hh < 2; hh++) {
        bbuf[nxt][hh * 2 + 0] = *(const float4*)(bp0 + jn + hh * 32);
        bbuf[nxt][hh * 2 + 1] = *(const float4*)(bp0 + jn + hh * 32 + 4);
        ujf[nxt][hh] = *(const f16x8*)(ujb + jn + hh * 32);
        u5f[nxt][hh] = *(const f16x8*)(u5b + jn + hh * 32);
      }
    }
    // compute current step: 2 halves of 32 j
    #pragma unroll
    for (int hh = 0; hh < 2; hh++) {
      const float4 v0 = bbuf[cur][hh * 2 + 0];
      const float4 v1 = bbuf[cur][hh * 2 + 1];
      const float g[8] = {v0.x, v0.y, v0.z, v0.w, v1.x, v1.y, v1.z, v1.w};
      f16x8 eb;
      #pragma unroll
      for (int j = 0; j < 8; j++)
        eb[j] = (_Float16)((g[j] == 0.f) ? 0.f : __expf(g[j]));
      const f16x8 a0 =
          eb * __builtin_elementwise_max(u58 * u5f[cur][hh], ui8 * ujf[cur][hh]);
      const int jo = st * 64 + hh * 32;
      #pragma unroll
      for (int dt = 0; dt < 4; dt++) {
        const f16x8 bfr = *(const f16x8*)(vb + (size_t)(dt * 16) * NN + jo);
        acc[dt] = __builtin_amdgcn_mfma_f32_16x16x32_f16(a0, bfr, acc[dt], 0, 0, 0);
      }
      acc[4] = __builtin_amdgcn_mfma_f32_16x16x32_f16(a0, kOne, acc[4], 0, 0, 0);
    }
  }

  const size_t lb = (size_t)(chunk * 4 + head) * NN + i0;
  if (m == 0) {
    #pragma unroll
    for (int r = 0; r < 4; r++) L[lb + quad * 4 + r] = acc[4][r];
  }
  const size_t pbase = ((size_t)(chunk * 4 + head) * NN + i0) * 64;
  #pragma unroll
  for (int dt = 0; dt < 4; dt++)
    #pragma unroll
    for (int r = 0; r < 4; r++)
      P[pbase + (size_t)(quad * 4 + r) * 64 + dt * 16 + m] = acc[dt][r];
}

// ---- Kernel 3: reduce partials, normalize, ELU ---------------------------
__global__ __launch_bounds__(256) void reduce_out(
    const float* __restrict__ P, const float* __restrict__ L,
    const float* __restrict__ Wh, float* __restrict__ out) {
  const int i0 = blockIdx.x * 16;
  const int h = blockIdx.y;
  const int t = threadIdx.x;
  const int d = t & 63;
  const int g = t >> 6;
  #pragma unroll
  for (int ii = 0; ii < 4; ii++) {
    const int i = i0 + g * 4 + ii;
    float lsum = 0.f, s = 0.f;
    #pragma unroll
    for (int c = 0; c < CH; c++) {
      lsum += L[(size_t)(c * 4 + h) * NN + i];
      s += P[((size_t)(c * 4 + h) * NN + i) * 64 + d];
    }
    const float wh = Wh[(size_t)i * 256 + h * 64 + d];
    const bool fb = (lsum == 0.f);
    float o = fb ? wh : s / lsum;
    o = (o > 0.f) ? o : (__expf(o) - 1.f);
    out[(size_t)i * 256 + h * 64 + d] = o;
  }
}

extern "C" void kernel_launch(void* const* d_in, const int* in_sizes, int n_in,
                              void* d_out, int out_size, void* d_ws, size_t ws_size,
                              hipStream_t stream) {
  const float* h_in = (const float*)d_in[0];   // (4096, 256)
  const float* adj  = (const float*)d_in[1];   // (4096, 4096)
  const float* W    = (const float*)d_in[2];   // (256, 256)
  const float* a    = (const float*)d_in[3];   // (4, 128)
  float* out = (float*)d_out;
  float* ws = (float*)d_ws;

  float* Wh = ws;
  _Float16* Vt   = (_Float16*)(ws + 1048576);
  _Float16* uit  = (_Float16*)(ws + 1048576 + 524288);
  _Float16* ui5t = uit + 16384;
  _Float16* ujt  = ui5t + 16384;
  _Float16* uj5t = ujt + 16384;
  _Float16* Wth  = (_Float16*)(ws + 1048576 + 524288 + 32768);
  _Float16* Wtl  = Wth + 65536;
  float* Lb = ws + 1048576 + 524288 + 32768 + 65536;
  float* Pb = Lb + (size_t)CH * 4 * 4096;

  hipLaunchKernelGGL(wtprep, dim3(16), dim3(256), 0, stream, W, Wth, Wtl);
  hipLaunchKernelGGL(gemm_wh, dim3(64, 4), dim3(256), 0, stream,
                     h_in, Wth, Wtl, a, Wh, Vt, uit, ui5t, ujt, uj5t);
  hipLaunchKernelGGL(gat_attn, dim3(256, CH), dim3(256), 0, stream,
                     adj, Vt, uit, ui5t, ujt, uj5t, Pb, Lb);
  hipLaunchKernelGGL(reduce_out, dim3(256, 4), dim3(256), 0, stream,
                     Pb, Lb, Wh, out);
}

// Round 9
// 163.589 us; speedup vs baseline: 1.2552x; 1.2552x over previous
//
#include <hip/hip_runtime.h>
#include <cstdint>
#include <cstddef>

// DenseGAT, N=4096, IN_DIM=256, H=4, D=64, NEG_SLOPE=0.2
// w[i,j,h] = eb * max(t5, tt);  tt = ui*uj, t5 = ui5*uj5 = tt^5 (exact),
//   eb = exp(bias) or 0 (masked), precomputed f16 by exp_bias.
// R9: gat_attn = m97-style async-DMA K-loop. global_load_lds stages eb
// tiles (compiler can't sink DMA; vmcnt in-order retire made register
// prefetch useless in R8). Vt frags preloaded pre-barrier -> compute has
// zero vmcnt waits. exp() hoisted out of the hot loop entirely.

typedef _Float16 f16x4 __attribute__((ext_vector_type(4)));
typedef _Float16 f16x8 __attribute__((ext_vector_type(8)));
typedef float f32x4 __attribute__((ext_vector_type(4)));

#define NN 4096
#define CH 8

__device__ __forceinline__ void dma16(const void* g, void* l) {
  __builtin_amdgcn_global_load_lds(
      (const __attribute__((address_space(1))) unsigned*)g,
      (__attribute__((address_space(3))) unsigned*)l, 16, 0, 0);
}

// ---- Kernel A: eb = exp(adj) (f16), 0 where masked -----------------------
__global__ __launch_bounds__(256) void exp_bias(const float* __restrict__ adj,
                                                _Float16* __restrict__ eb) {
  const size_t base = ((size_t)blockIdx.x * 256 + threadIdx.x) * 16;
  float4 v[4];
  #pragma unroll
  for (int q = 0; q < 4; q++) v[q] = *(const float4*)(adj + base + q * 4);
  const float* g = (const float*)v;
  f16x8 e0, e1;
  #pragma unroll
  for (int k = 0; k < 8; k++) {
    e0[k] = (_Float16)((g[k] == 0.f) ? 0.f : __expf(g[k]));
    e1[k] = (_Float16)((g[8 + k] == 0.f) ? 0.f : __expf(g[8 + k]));
  }
  *(f16x8*)(eb + base) = e0;
  *(f16x8*)(eb + base + 8) = e1;
}

// ---- Kernel 0: transpose + hi/lo split W ---------------------------------
__global__ __launch_bounds__(256) void wtprep(const float* __restrict__ W,
                                              _Float16* __restrict__ Wth,
                                              _Float16* __restrict__ Wtl) {
  __shared__ float s[64][65];
  const int t = threadIdx.x;
  const int kt = blockIdx.x >> 2, ct = blockIdx.x & 3;
  {
    const int r = t >> 2, cq = (t & 3) * 16;
    #pragma unroll
    for (int q = 0; q < 4; q++) {
      float4 v = *(const float4*)&W[(size_t)(kt * 64 + r) * 256 + ct * 64 + cq + q * 4];
      s[r][cq + q * 4 + 0] = v.x; s[r][cq + q * 4 + 1] = v.y;
      s[r][cq + q * 4 + 2] = v.z; s[r][cq + q * 4 + 3] = v.w;
    }
  }
  __syncthreads();
  {
    const int c = t >> 2, kq = (t & 3) * 16;
    f16x8 hi[2], lo[2];
    #pragma unroll
    for (int g = 0; g < 2; g++)
      #pragma unroll
      for (int kk = 0; kk < 8; kk++) {
        float wv = s[kq + g * 8 + kk][c];
        _Float16 hh = (_Float16)wv;
        hi[g][kk] = hh;
        lo[g][kk] = (_Float16)((wv - (float)hh) * 2048.0f);
      }
    const size_t base = (size_t)(ct * 64 + c) * 256 + kt * 64 + kq;
    *(f16x8*)&Wth[base] = hi[0]; *(f16x8*)&Wth[base + 8] = hi[1];
    *(f16x8*)&Wtl[base] = lo[0]; *(f16x8*)&Wtl[base + 8] = lo[1];
  }
}

// ---- Kernel 1: Wh = h @ W via MFMA hi/lo split; + Vt, ui/uj exps ---------
__global__ __launch_bounds__(256) void gemm_wh(
    const float* __restrict__ A, const _Float16* __restrict__ Wth,
    const _Float16* __restrict__ Wtl, const float* __restrict__ av,
    float* __restrict__ Wh, _Float16* __restrict__ Vt,
    _Float16* __restrict__ uit, _Float16* __restrict__ ui5t,
    _Float16* __restrict__ ujt, _Float16* __restrict__ uj5t) {
  const int tid = threadIdx.x;
  const int lane = tid & 63;
  const int w = __builtin_amdgcn_readfirstlane(tid >> 6);
  const int m = lane & 15, quad = lane >> 4;
  const int mt = blockIdx.x;
  const int head = blockIdx.y;
  const int arow = mt * 64 + w * 16 + m;

  f32x4 dhi[4], dlo[4];
  #pragma unroll
  for (int nt = 0; nt < 4; nt++)
    #pragma unroll
    for (int r = 0; r < 4; r++) { dhi[nt][r] = 0.f; dlo[nt][r] = 0.f; }

  #pragma unroll
  for (int ks = 0; ks < 8; ks++) {
    const float* ap = A + (size_t)arow * 256 + ks * 32 + quad * 8;
    float4 v0 = *(const float4*)ap;
    float4 v1 = *(const float4*)(ap + 4);
    const float vv[8] = {v0.x, v0.y, v0.z, v0.w, v1.x, v1.y, v1.z, v1.w};
    f16x8 ah, al;
    #pragma unroll
    for (int j = 0; j < 8; j++) {
      _Float16 hh = (_Float16)vv[j];
      ah[j] = hh;
      al[j] = (_Float16)((vv[j] - (float)hh) * 2048.0f);
    }
    #pragma unroll
    for (int nt = 0; nt < 4; nt++) {
      const size_t base = (size_t)(head * 64 + nt * 16 + m) * 256 + ks * 32 + quad * 8;
      f16x8 bh = *(const f16x8*)&Wth[base];
      f16x8 bl = *(const f16x8*)&Wtl[base];
      dhi[nt] = __builtin_amdgcn_mfma_f32_16x16x32_f16(ah, bh, dhi[nt], 0, 0, 0);
      dlo[nt] = __builtin_amdgcn_mfma_f32_16x16x32_f16(al, bh, dlo[nt], 0, 0, 0);
      dlo[nt] = __builtin_amdgcn_mfma_f32_16x16x32_f16(ah, bl, dlo[nt], 0, 0, 0);
    }
  }

  f32x4 C[4];
  #pragma unroll
  for (int nt = 0; nt < 4; nt++)
    #pragma unroll
    for (int r = 0; r < 4; r++) C[nt][r] = dhi[nt][r] + dlo[nt][r] * (1.0f / 2048.0f);

  const int crow0 = mt * 64 + w * 16 + quad * 4;
  #pragma unroll
  for (int nt = 0; nt < 4; nt++) {
    #pragma unroll
    for (int r = 0; r < 4; r++)
      Wh[(size_t)(crow0 + r) * 256 + head * 64 + nt * 16 + m] = C[nt][r];
    f16x4 tv;
    #pragma unroll
    for (int r = 0; r < 4; r++) tv[r] = (_Float16)C[nt][r];
    *(f16x4*)&Vt[(size_t)(head * 64 + nt * 16 + m) * NN + crow0] = tv;
  }

  float ai[4], aj[4];
  #pragma unroll
  for (int nt = 0; nt < 4; nt++) {
    ai[nt] = av[head * 128 + nt * 16 + m];
    aj[nt] = av[head * 128 + 64 + nt * 16 + m];
  }
  #pragma unroll
  for (int r = 0; r < 4; r++) {
    float si = 0.f, sj = 0.f;
    #pragma unroll
    for (int nt = 0; nt < 4; nt++) {
      si = fmaf(C[nt][r], ai[nt], si);
      sj = fmaf(C[nt][r], aj[nt], sj);
    }
    #pragma unroll
    for (int msk = 1; msk <= 8; msk <<= 1) {
      si += __shfl_xor(si, msk, 64);
      sj += __shfl_xor(sj, msk, 64);
    }
    if (m == 0) {
      const int row = crow0 + r;
      uit [(size_t)head * NN + row] = (_Float16)__expf(0.2f * si);
      ui5t[(size_t)head * NN + row] = (_Float16)__expf(si);
      ujt [(size_t)head * NN + row] = (_Float16)__expf(0.2f * sj);
      uj5t[(size_t)head * NN + row] = (_Float16)__expf(sj);
    }
  }
}

// ---- Kernel 2: fused attention, async-DMA staged eb ----------------------
// grid (128 i-tiles of 32, 8 j-chunks of 512), block 256 = 4 waves (= head).
// K-loop per 64 j: preload Vt (pre-barrier) -> barrier (drains DMA+Vt) ->
// issue DMA(next eb tile) -> compute purely from regs+LDS (no vmcnt waits).
__global__ __launch_bounds__(256, 4) void gat_attn(
    const _Float16* __restrict__ eb, const _Float16* __restrict__ Vt,
    const _Float16* __restrict__ uit, const _Float16* __restrict__ ui5t,
    const _Float16* __restrict__ ujt, const _Float16* __restrict__ uj5t,
    float* __restrict__ P, float* __restrict__ L) {
  __shared__ _Float16 tile[2][32 * 64];   // eb tile, col-rotated by 8*(row&7)
  __shared__ _Float16 suj[4 * 512];
  __shared__ _Float16 suj5[4 * 512];
  const int itile = blockIdx.x, chunk = blockIdx.y;
  const int tid = threadIdx.x, lane = tid & 63;
  const int head = __builtin_amdgcn_readfirstlane(tid >> 6);
  const int m = lane & 15, q = lane >> 4;
  const int i0 = itile * 32, j0 = chunk * 512;

  // uj/uj5 chunk -> LDS (one f16x8 per lane per array)
  *(f16x8*)&suj [head * 512 + lane * 8] =
      *(const f16x8*)&ujt [(size_t)head * NN + j0 + lane * 8];
  *(f16x8*)&suj5[head * 512 + lane * 8] =
      *(const f16x8*)&uj5t[(size_t)head * NN + j0 + lane * 8];

  // DMA geometry: wave w stages tile rows 8w..8w+7 (1 issue, 16 B/lane)
  const int srow = head * 8 + (lane >> 3);
  const int c8 = (lane & 7) * 8;
  const int jrot = (c8 - 8 * (srow & 7)) & 63;     // inverse column rotation
  const _Float16* gsrc = eb + (size_t)(i0 + srow) * NN + j0 + jrot;
  _Float16* ldst0 = &tile[0][head * 512];
  _Float16* ldst1 = &tile[1][head * 512];

  dma16(gsrc, ldst0);   // stage jc = 0

  f32x4 acc[10];        // [r0 dt0..3][r1 dt0..3][ones r0][ones r1]
  #pragma unroll
  for (int a = 0; a < 10; a++)
    #pragma unroll
    for (int r = 0; r < 4; r++) acc[a][r] = 0.f;

  const _Float16 ui_0 = uit [(size_t)head * NN + i0 + m];
  const _Float16 ui_1 = uit [(size_t)head * NN + i0 + 16 + m];
  const _Float16 u5_0 = ui5t[(size_t)head * NN + i0 + m];
  const _Float16 u5_1 = ui5t[(size_t)head * NN + i0 + 16 + m];
  const f16x8 ui8_0 = {ui_0, ui_0, ui_0, ui_0, ui_0, ui_0, ui_0, ui_0};
  const f16x8 ui8_1 = {ui_1, ui_1, ui_1, ui_1, ui_1, ui_1, ui_1, ui_1};
  const f16x8 u58_0 = {u5_0, u5_0, u5_0, u5_0, u5_0, u5_0, u5_0, u5_0};
  const f16x8 u58_1 = {u5_1, u5_1, u5_1, u5_1, u5_1, u5_1, u5_1, u5_1};
  const f16x8 kOne = {(_Float16)1.f, (_Float16)1.f, (_Float16)1.f, (_Float16)1.f,
                      (_Float16)1.f, (_Float16)1.f, (_Float16)1.f, (_Float16)1.f};

  const _Float16* vbase = Vt + (size_t)(head * 64 + m) * NN + j0 + q * 8;
  const int ebrot = 8 * (m & 7);                   // read-side rotation

  for (int jc = 0; jc < 8; jc++) {
    const int buf = jc & 1;
    // Vt fragments for this jc — issued BEFORE the barrier so the barrier's
    // vmcnt(0) completes them; compute below has no vmem waits at all.
    f16x8 bv[8];
    #pragma unroll
    for (int s = 0; s < 2; s++)
      #pragma unroll
      for (int dt = 0; dt < 4; dt++)
        bv[s * 4 + dt] =
            *(const f16x8*)(vbase + (size_t)(dt * 16) * NN + jc * 64 + s * 32);
    __syncthreads();                               // tile jc + bv ready
    if (jc < 7) dma16(gsrc + (jc + 1) * 64, buf ? ldst0 : ldst1);
    #pragma unroll
    for (int s = 0; s < 2; s++) {
      const int cr = (s * 32 + q * 8 + ebrot) & 63;
      const f16x8 e0 = *(const f16x8*)&tile[buf][m * 64 + cr];
      const f16x8 e1 = *(const f16x8*)&tile[buf][(m + 16) * 64 + cr];
      const int jcol = head * 512 + jc * 64 + s * 32 + q * 8;
      const f16x8 uj8  = *(const f16x8*)&suj[jcol];    // same-addr broadcast
      const f16x8 uj58 = *(const f16x8*)&suj5[jcol];
      const f16x8 a0 = e0 * __builtin_elementwise_max(u58_0 * uj58, ui8_0 * uj8);
      const f16x8 a1 = e1 * __builtin_elementwise_max(u58_1 * uj58, ui8_1 * uj8);
      #pragma unroll
      for (int dt = 0; dt < 4; dt++) {
        acc[dt]     = __builtin_amdgcn_mfma_f32_16x16x32_f16(a0, bv[s * 4 + dt], acc[dt], 0, 0, 0);
        acc[4 + dt] = __builtin_amdgcn_mfma_f32_16x16x32_f16(a1, bv[s * 4 + dt], acc[4 + dt], 0, 0, 0);
      }
      acc[8] = __builtin_amdgcn_mfma_f32_16x16x32_f16(a0, kOne, acc[8], 0, 0, 0);
      acc[9] = __builtin_amdgcn_mfma_f32_16x16x32_f16(a1, kOne, acc[9], 0, 0, 0);
    }
  }

  const size_t lb = (size_t)(chunk * 4 + head) * NN + i0;
  if (m == 0) {
    #pragma unroll
    for (int r = 0; r < 4; r++) {
      L[lb + q * 4 + r] = acc[8][r];
      L[lb + 16 + q * 4 + r] = acc[9][r];
    }
  }
  const size_t pbase = ((size_t)(chunk * 4 + head) * NN + i0) * 64;
  #pragma unroll
  for (int it = 0; it < 2; it++)
    #pragma unroll
    for (int dt = 0; dt < 4; dt++)
      #pragma unroll
      for (int r = 0; r < 4; r++)
        P[pbase + (size_t)(it * 16 + q * 4 + r) * 64 + dt * 16 + m] =
            acc[it * 4 + dt][r];
}

// ---- Kernel 3: reduce partials, normalize, ELU ---------------------------
__global__ __launch_bounds__(256) void reduce_out(
    const float* __restrict__ P, const float* __restrict__ L,
    const float* __restrict__ Wh, float* __restrict__ out) {
  const int i0 = blockIdx.x * 16;
  const int h = blockIdx.y;
  const int t = threadIdx.x;
  const int d = t & 63;
  const int g = t >> 6;
  #pragma unroll
  for (int ii = 0; ii < 4; ii++) {
    const int i = i0 + g * 4 + ii;
    float lsum = 0.f, s = 0.f;
    #pragma unroll
    for (int c = 0; c < CH; c++) {
      lsum += L[(size_t)(c * 4 + h) * NN + i];
      s += P[((size_t)(c * 4 + h) * NN + i) * 64 + d];
    }
    const float wh = Wh[(size_t)i * 256 + h * 64 + d];
    const bool fb = (lsum == 0.f);
    float o = fb ? wh : s / lsum;
    o = (o > 0.f) ? o : (__expf(o) - 1.f);
    out[(size_t)i * 256 + h * 64 + d] = o;
  }
}

extern "C" void kernel_launch(void* const* d_in, const int* in_sizes, int n_in,
                              void* d_out, int out_size, void* d_ws, size_t ws_size,
                              hipStream_t stream) {
  const float* h_in = (const float*)d_in[0];   // (4096, 256)
  const float* adj  = (const float*)d_in[1];   // (4096, 4096)
  const float* W    = (const float*)d_in[2];   // (256, 256)
  const float* a    = (const float*)d_in[3];   // (4, 128)
  float* out = (float*)d_out;
  float* ws = (float*)d_ws;

  float* Wh = ws;
  _Float16* Vt   = (_Float16*)(ws + 1048576);
  _Float16* uit  = (_Float16*)(ws + 1048576 + 524288);
  _Float16* ui5t = uit + 16384;
  _Float16* ujt  = ui5t + 16384;
  _Float16* uj5t = ujt + 16384;
  _Float16* Wth  = (_Float16*)(ws + 1048576 + 524288 + 32768);
  _Float16* Wtl  = Wth + 65536;
  float* Lb = ws + 1048576 + 524288 + 32768 + 65536;          // CH*4*4096
  float* Pb = Lb + (size_t)CH * 4 * 4096;                     // CH*4*4096*64
  _Float16* ebp = (_Float16*)(Pb + (size_t)CH * 4 * 4096 * 64);

  hipLaunchKernelGGL(exp_bias, dim3(4096), dim3(256), 0, stream, adj, ebp);
  hipLaunchKernelGGL(wtprep, dim3(16), dim3(256), 0, stream, W, Wth, Wtl);
  hipLaunchKernelGGL(gemm_wh, dim3(64, 4), dim3(256), 0, stream,
                     h_in, Wth, Wtl, a, Wh, Vt, uit, ui5t, ujt, uj5t);
  hipLaunchKernelGGL(gat_attn, dim3(128, CH), dim3(256), 0, stream,
                     ebp, Vt, uit, ui5t, ujt, uj5t, Pb, Lb);
  hipLaunchKernelGGL(reduce_out, dim3(256, 4), dim3(256), 0, stream,
                     Pb, Lb, Wh, out);
}